// Round 12
// baseline (220.527 us; speedup 1.0000x reference)
//
#include <hip/hip_runtime.h>
#include <hip/hip_bf16.h>
#include <hip/hip_fp16.h>

#define DIM 96
#define EBLK 256          // partition blocks per edge set
typedef unsigned int u32;
typedef unsigned long long u64;
typedef __attribute__((ext_vector_type(8))) _Float16 half8;
typedef __attribute__((ext_vector_type(4))) float f32x4;

__device__ __forceinline__ unsigned short f2h(float f) {
    union { unsigned short s; _Float16 h; } v; v.h = (_Float16)f; return v.s;
}
__device__ __forceinline__ u32 pkh(float lo, float hi) {
    return (u32)f2h(lo) | ((u32)f2h(hi) << 16);
}
__device__ __forceinline__ float hl(u32 u) {
    union { unsigned short s; _Float16 h; } v; v.s = (unsigned short)u; return (float)v.h;
}
__device__ __forceinline__ float hh(u32 u) {
    union { unsigned short s; _Float16 h; } v; v.s = (unsigned short)(u >> 16); return (float)v.h;
}

struct __align__(4) U3 { u32 a, b, c; };

// ---- setup: cast X -> fp16; bounds via unique-writer stores; zero out + cursor ----
__global__ __launch_bounds__(256) void k_cast0(
    const float* __restrict__ x, u32* __restrict__ Xh,
    const int* __restrict__ batch, int* __restrict__ gs, int* __restrict__ ge,
    float* __restrict__ outp, u32* __restrict__ cursor,
    int n, int total8, int osz)
{
    int i = blockIdx.x * 256 + threadIdx.x;
    if (i < total8) {
        const float4* xv = (const float4*)x;
        float4 a = xv[i * 2], b = xv[i * 2 + 1];
        uint4 o;
        o.x = pkh(a.x, a.y); o.y = pkh(a.z, a.w);
        o.z = pkh(b.x, b.y); o.w = pkh(b.z, b.w);
        ((uint4*)Xh)[i] = o;
    }
    if (i < n) {
        int b = batch[i];
        if (i == 0 || batch[i - 1] != b) gs[b] = i;        // unique writer
        if (i == n - 1 || batch[i + 1] != b) ge[b] = i + 1; // unique writer
    }
    if (i < osz) outp[i] = 0.f;
    if (i == 0) { cursor[0] = 0; cursor[1] = 0; }
}

// ---- pass A: per-block LDS histogram over buckets (dst>>7); extra blocks = combine ----
__global__ __launch_bounds__(256) void k_hist(
    const int* __restrict__ ei, const int* __restrict__ ein,
    u32* __restrict__ cntmat, int E, int n, int NB, int epb,
    const float* __restrict__ W0o, const float* __restrict__ W0n, const float* __restrict__ W0f,
    const float* __restrict__ b0o, const float* __restrict__ b0n, const float* __restrict__ b0f,
    const float* __restrict__ W1o, const float* __restrict__ W1n, const float* __restrict__ W1f,
    const float* __restrict__ b1o, const float* __restrict__ b1n, const float* __restrict__ b1f,
    unsigned short* __restrict__ Wt, float* __restrict__ bc,
    const int* __restrict__ gs, const int* __restrict__ ge, float* __restrict__ rinv)
{
    int set = blockIdx.y, tid = threadIdx.x;
    if (blockIdx.x >= EBLK) {
        // ---- fused k_combine (layer = blockIdx.y) ----
        if (blockIdx.y == 0 && blockIdx.x == EBLK && tid < 64) {
            int c = ge[tid] - gs[tid];
            if (c < 1) c = 1;
            rinv[tid] = 1.0f / (float)c;
        }
        int l = blockIdx.y;
        const float* Wo = l ? W1o : W0o;
        const float* Wn = l ? W1n : W0n;
        const float* Wf = l ? W1f : W0f;
        const float* bo = l ? b1o : b0o;
        const float* bn = l ? b1n : b0n;
        const float* bf = l ? b1f : b0f;
        unsigned short* wt = Wt + (size_t)l * 96 * 192;
        float* bcl = bc + l * DIM;
        int g = (blockIdx.x - EBLK) * 256 + tid;
        if (g >= DIM * DIM) return;
        int i = g / DIM, j = g % DIM;
        float so = 0.f, sn = 0.f;
        for (int k = 0; k < DIM; ++k) {
            so += Wo[i * DIM + k] * Wf[k * DIM + j];
            sn += Wn[i * DIM + k] * Wf[(DIM + k) * DIM + j];
        }
        wt[j * 192 + i]      = f2h(so);
        wt[j * 192 + 96 + i] = f2h(sn);
        if (i == 0) {
            float s = bf[j];
            for (int k = 0; k < DIM; ++k)
                s += bo[k] * Wf[k * DIM + j] + bn[k] * Wf[(DIM + k) * DIM + j];
            bcl[j] = s;
        }
        return;
    }
    __shared__ u32 hist[512];
    for (int t = tid; t < NB; t += 256) hist[t] = 0;
    __syncthreads();
    const int* D = (set ? ein : ei) + E;
    int lo = blockIdx.x * epb, hi = min(E, lo + epb);
    for (int e = lo + tid; e < hi; e += 256)
        atomicAdd(&hist[((u32)D[e]) >> 7], 1u);
    __syncthreads();
    u32* cm = cntmat + (size_t)set * NB * EBLK;
    for (int t = tid; t < NB; t += 256)
        cm[(size_t)t * EBLK + blockIdx.x] = hist[t];
}

// ---- pass B: per-bucket scan of 256 block counts; bucket base via cursor ----
__global__ __launch_bounds__(256) void k_bscan(
    const u32* __restrict__ cntmat, u32* __restrict__ ebase,
    u64* __restrict__ binfo, u32* __restrict__ cursor, int NB)
{
    int set = blockIdx.y, b = blockIdx.x, tid = threadIdx.x;
    int lane = tid & 63, wv = tid >> 6;
    const u32* cm = cntmat + ((size_t)set * NB + b) * EBLK;
    u32 v = cm[tid];
    u32 incl = v;
    #pragma unroll
    for (int d = 1; d < 64; d <<= 1) {
        u32 t = __shfl_up(incl, d);
        if (lane >= d) incl += t;
    }
    __shared__ u32 wt[4], woff[4], base_s;
    if (lane == 63) wt[wv] = incl;
    __syncthreads();
    if (tid == 0) {
        u32 run = 0;
        #pragma unroll
        for (int k = 0; k < 4; ++k) { woff[k] = run; run += wt[k]; }
        base_s = atomicAdd(&cursor[set], run);
        binfo[(size_t)set * NB + b] = ((u64)run << 32) | (u64)base_s;
    }
    __syncthreads();
    ebase[((size_t)set * NB + b) * EBLK + tid] = base_s + woff[wv] + incl - v;
}

// ---- pass C: partition edges into buckets: evb = [w32 | dl:7 | src:17] ----
__global__ __launch_bounds__(256) void k_part(
    const int* __restrict__ ei, const float* __restrict__ ew,
    const int* __restrict__ ein, const float* __restrict__ ewn,
    const u32* __restrict__ ebase, u64* __restrict__ evb,
    int E, int NB, int epb)
{
    int set = blockIdx.y, tid = threadIdx.x;
    const int*   I = set ? ein : ei;
    const float* W = set ? ewn : ew;
    __shared__ u32 hb[512];
    const u32* eb = ebase + (size_t)set * NB * EBLK;
    for (int t = tid; t < NB; t += 256) hb[t] = eb[(size_t)t * EBLK + blockIdx.x];
    __syncthreads();
    u64* out = evb + (size_t)set * E;
    int lo = blockIdx.x * epb, hi = min(E, lo + epb);
    for (int e = lo + tid; e < hi; e += 256) {
        int s = I[e], d = I[E + e];
        u32 wbits = __float_as_uint(W[e]);
        u32 pos = atomicAdd(&hb[(u32)d >> 7], 1u);
        out[pos] = ((u64)wbits << 32) | ((u32)(d & 127) << 17) | (u32)s;
    }
}

// ---- pass D: per-bucket node counts + weight sums (LDS) -> seg, dinv ----
__global__ __launch_bounds__(256) void k_nprep(
    const u64* __restrict__ evb, const u64* __restrict__ binfo,
    u64* __restrict__ seg, float* __restrict__ dinv, int E, int n, int NB)
{
    int set = blockIdx.y, b = blockIdx.x, tid = threadIdx.x;
    __shared__ u64 acc[128];
    if (tid < 128) acc[tid] = 0;
    __syncthreads();
    u64 bi = binfo[(size_t)set * NB + b];
    u32 base = (u32)bi, tot = (u32)(bi >> 32);
    const u64* ev = evb + (size_t)set * E;
    for (u32 j = tid; j < tot; j += 256) {
        u64 p = ev[base + j];
        u32 dl = ((u32)p >> 17) & 127;
        float w = __uint_as_float((u32)(p >> 32));
        u32 wfix = (u32)(w * 16777216.0f + 0.5f);
        atomicAdd(&acc[dl], ((u64)1 << 32) | (u64)wfix);
    }
    __syncthreads();
    __shared__ u32 wtot;
    u32 cnt = 0, excl = 0;
    if (tid < 128) {
        u64 a = acc[tid];
        cnt = (u32)(a >> 32);
        u32 incl = cnt;
        #pragma unroll
        for (int d = 1; d < 64; d <<= 1) {
            u32 t = __shfl_up(incl, d);
            if ((tid & 63) >= d) incl += t;
        }
        if (tid == 63) wtot = incl;
        excl = incl - cnt;
    }
    __syncthreads();
    if (tid >= 64 && tid < 128) excl += wtot;
    int gnode = b * 128 + tid;
    if (tid < 128 && gnode < n) {
        u32 st = base + excl;
        seg[(size_t)set * n + gnode] = ((u64)(st + cnt) << 32) | (u64)st;
        u64 a = acc[tid];
        dinv[(size_t)set * n + gnode] =
            rsqrtf((float)(u32)a * 5.9604644775390625e-8f + 1.0f);
    }
}

// ---- pass E: bucket -> node-exact CSR with norm folded: ev = [norm_f32 | src] ----
__global__ __launch_bounds__(256) void k_scat2(
    const u64* __restrict__ evb, const u64* __restrict__ binfo,
    const u64* __restrict__ seg, const float* __restrict__ dinv,
    u64* __restrict__ evout, int E, int n, int NB)
{
    int set = blockIdx.y, b = blockIdx.x, tid = threadIdx.x;
    __shared__ u32 rk[128];
    __shared__ u32 st_l[128];
    __shared__ float dv_l[128];
    const float* dv = dinv + (size_t)set * n;
    if (tid < 128) {
        rk[tid] = 0;
        int gnode = b * 128 + tid;
        if (gnode < n) {
            st_l[tid] = (u32)seg[(size_t)set * n + gnode];
            dv_l[tid] = dv[gnode];
        }
    }
    __syncthreads();
    u64 bi = binfo[(size_t)set * NB + b];
    u32 base = (u32)bi, tot = (u32)(bi >> 32);
    const u64* evi = evb + (size_t)set * E;
    u64* out = evout + (size_t)set * E;
    for (u32 j = tid; j < tot; j += 256) {
        u64 p = evi[base + j];
        u32 src = (u32)p & 0x1ffffu;
        u32 dl = ((u32)p >> 17) & 127;
        float w = __uint_as_float((u32)(p >> 32));
        float nrm = dv_l[dl] * w * dv[src];
        u32 slot = st_l[dl] + atomicAdd(&rk[dl], 1u);
        out[slot] = ((u64)__float_as_uint(nrm) << 32) | (u64)src;
    }
}

// ------- aggregation: 4 edge-groups x 16 lanes; predicated 8-slot batch gather -------
__global__ __launch_bounds__(256) void k_agg(
    const u32* __restrict__ Xh,
    const u64* __restrict__ seg,
    const u64* __restrict__ ev_o, const u64* __restrict__ ev_n,
    const float* __restrict__ dinv,
    u32* __restrict__ fAB, int n)
{
    int wid = (blockIdx.x * 256 + threadIdx.x) >> 6;
    if (wid >= n) return;
    int lane = threadIdx.x & 63;
    int g = lane >> 4, sl = lane & 15;
    const u64* ev; const u64* sg; const float* dv; int co;
    if (blockIdx.y) { sg = seg + n; ev = ev_n; dv = dinv + n; co = 48; }
    else            { sg = seg;     ev = ev_o; dv = dinv;     co = 0; }

    float a0=0,a1=0,a2=0,a3=0,a4=0,a5=0;
    if (g == 0) {
        float dr = dv[wid];
        float d2 = dr * dr;
        U3 xv = *(const U3*)(Xh + (size_t)wid * 48 + sl * 3);
        a0 = d2 * hl(xv.a); a1 = d2 * hh(xv.a);
        a2 = d2 * hl(xv.b); a3 = d2 * hh(xv.b);
        a4 = d2 * hl(xv.c); a5 = d2 * hh(xv.c);
    }
    u64 sv = sg[wid];
    int s = (int)(u32)sv, e = (int)(u32)(sv >> 32);
    if (e > s) {
        int j0 = s + g;
        // 8 predicated slots, stride 4: all ev loads independent, then all gathers
        float ww[8]; int uu[8];
        #pragma unroll
        for (int k = 0; k < 8; ++k) {
            int j = j0 + k * 4;
            int jc = j < e ? j : s;          // clamp to valid slot
            u64 t = ev[jc];
            ww[k] = (j < e) ? __uint_as_float((u32)(t >> 32)) : 0.f;
            uu[k] = (int)(u32)t;
        }
        U3 xx[8];
        #pragma unroll
        for (int k = 0; k < 8; ++k)
            xx[k] = *(const U3*)(Xh + (size_t)uu[k] * 48 + sl * 3);
        #pragma unroll
        for (int k = 0; k < 8; ++k) {
            float w = ww[k];
            a0 += w * hl(xx[k].a); a1 += w * hh(xx[k].a);
            a2 += w * hl(xx[k].b); a3 += w * hh(xx[k].b);
            a4 += w * hl(xx[k].c); a5 += w * hh(xx[k].c);
        }
        // rare tail: per-group edges beyond 8
        for (int j = j0 + 32; j < e; j += 4) {
            u64 ee = ev[j];
            int u = (int)(u32)ee;
            float w = __uint_as_float((u32)(ee >> 32));
            U3 xv = *(const U3*)(Xh + (size_t)u * 48 + sl * 3);
            a0 += w * hl(xv.a); a1 += w * hh(xv.a);
            a2 += w * hl(xv.b); a3 += w * hh(xv.b);
            a4 += w * hl(xv.c); a5 += w * hh(xv.c);
        }
    }
    a0 += __shfl_xor(a0, 32); a1 += __shfl_xor(a1, 32); a2 += __shfl_xor(a2, 32);
    a3 += __shfl_xor(a3, 32); a4 += __shfl_xor(a4, 32); a5 += __shfl_xor(a5, 32);
    a0 += __shfl_xor(a0, 16); a1 += __shfl_xor(a1, 16); a2 += __shfl_xor(a2, 16);
    a3 += __shfl_xor(a3, 16); a4 += __shfl_xor(a4, 16); a5 += __shfl_xor(a5, 16);
    if (g == 0) {
        U3 o;
        o.a = pkh(a0, a1); o.b = pkh(a2, a3); o.c = pkh(a4, a5);
        *(U3*)(fAB + (size_t)wid * 96 + co + sl * 3) = o;
    }
}

// ---------------- MFMA GEMM: relu(fAB[N][192]fp16 @ Wt + bias); pool; fp16 H ----------------
__global__ __launch_bounds__(256) void k_mmp(
    const u32* __restrict__ fAB, const unsigned short* __restrict__ Wtg,
    const float* __restrict__ bias, const int* __restrict__ batch,
    const int* __restrict__ gs, const int* __restrict__ ge,
    const float* __restrict__ rinv, float* __restrict__ outp,
    u32* __restrict__ Hh, int writeH, int n)
{
    __shared__ unsigned short sW[96 * 200];
    __shared__ float tile[64][100];
    int tid = threadIdx.x;
    for (int m = tid; m < 2304; m += 256) {
        int j = m / 24, k = (m % 24) * 8;
        *(uint4*)&sW[j * 200 + k] = *(const uint4*)&Wtg[j * 192 + k];
    }
    __syncthreads();
    int r0 = blockIdx.x * 64;
    int rows = min(64, n - r0);
    int lane = tid & 63, wv = tid >> 6;
    int rl = lane & 15;
    int kg = lane >> 4;
    int rowg = r0 + wv * 16 + rl;
    int rc = min(rowg, n - 1);
    const half8* Arow = (const half8*)(fAB + (size_t)rc * 96);
    f32x4 acc[6];
    #pragma unroll
    for (int c = 0; c < 6; ++c) acc[c] = (f32x4){0.f, 0.f, 0.f, 0.f};
    #pragma unroll
    for (int t = 0; t < 6; ++t) {
        half8 a = Arow[t * 4 + kg];
        #pragma unroll
        for (int c = 0; c < 6; ++c) {
            half8 b = *(const half8*)&sW[(c * 16 + rl) * 200 + t * 32 + kg * 8];
            acc[c] = __builtin_amdgcn_mfma_f32_16x16x32_f16(a, b, acc[c], 0, 0, 0);
        }
    }
    #pragma unroll
    for (int c = 0; c < 6; ++c) {
        int col = c * 16 + rl;
        float bs = bias[col];
        #pragma unroll
        for (int q = 0; q < 4; ++q) {
            int lr = wv * 16 + kg * 4 + q;
            tile[lr][col] = fmaxf(acc[c][q] + bs, 0.f);
        }
    }
    __syncthreads();
    if (writeH) {
        for (int m = tid; m < rows * 48; m += 256) {
            int row = m / 48, cp = m % 48;
            Hh[(size_t)(r0 + row) * 48 + cp] = pkh(tile[row][cp * 2], tile[row][cp * 2 + 1]);
        }
    }
    if (tid < DIM) {
        int gfirst = batch[r0], glast = batch[r0 + rows - 1];
        for (int g = gfirst; g <= glast; ++g) {
            int lo = max(gs[g] - r0, 0), hi = min(ge[g] - r0, rows);
            if (lo < hi) {
                float s = 0.f;
                for (int r = lo; r < hi; ++r) s += tile[r][tid];
                atomicAdd(&outp[g * DIM + tid], s * rinv[g]);
            }
        }
    }
}

extern "C" void kernel_launch(void* const* d_in, const int* in_sizes, int n_in,
                              void* d_out, int out_size, void* d_ws, size_t ws_size,
                              hipStream_t stream)
{
    const float* x     = (const float*)d_in[0];
    const int*   ei    = (const int*)d_in[1];
    const float* ew    = (const float*)d_in[2];
    const int*   batch = (const int*)d_in[3];
    const int*   ein   = (const int*)d_in[4];
    const float* ewn   = (const float*)d_in[5];
    const float* W0o = (const float*)d_in[7];
    const float* b0o = (const float*)d_in[8];
    const float* W0n = (const float*)d_in[9];
    const float* b0n = (const float*)d_in[10];
    const float* W0f = (const float*)d_in[11];
    const float* b0f = (const float*)d_in[12];
    const float* W1o = (const float*)d_in[13];
    const float* b1o = (const float*)d_in[14];
    const float* W1n = (const float*)d_in[15];
    const float* b1n = (const float*)d_in[16];
    const float* W1f = (const float*)d_in[17];
    const float* b1f = (const float*)d_in[18];

    const int N = in_sizes[0] / DIM;
    const int E = in_sizes[2];
    float* out = (float*)d_out;
    const int NB = (N + 127) >> 7;
    const int epb = (E + EBLK - 1) / EBLK;

    char* ws = (char*)d_ws;
    size_t off = 0;
    auto alloc = [&](size_t bytes) -> char* {
        char* p = ws + off;
        off += (bytes + 255) & ~(size_t)255;
        return p;
    };
    u32*   cntmat = (u32*)alloc((size_t)2 * NB * EBLK * 4);
    u32*   ebase  = (u32*)alloc((size_t)2 * NB * EBLK * 4);
    u64*   binfo  = (u64*)alloc((size_t)2 * NB * 8);
    u64*   evb    = (u64*)alloc((size_t)2 * E * 8);
    u64*   ev     = (u64*)alloc((size_t)2 * E * 8);
    u64*   seg    = (u64*)alloc((size_t)2 * N * 8);
    float* dinv   = (float*)alloc((size_t)2 * N * 4);
    u32*   Xh     = (u32*)alloc((size_t)N * 48 * 4);
    u32*   Hh     = (u32*)alloc((size_t)N * 48 * 4);
    u32*   fAB    = (u32*)alloc((size_t)N * 96 * 4);
    unsigned short* Wt = (unsigned short*)alloc((size_t)2 * 96 * 192 * 2);
    float* bc     = (float*)alloc(2 * DIM * 4);
    float* rinv   = (float*)alloc(64 * 4);
    int*   gs     = (int*)alloc(64 * 4);
    int*   ge     = (int*)alloc(64 * 4);
    u32*   cursor = (u32*)alloc(2 * 4);

    // 1) setup: cast + bounds + zero out/cursor
    k_cast0<<<(N * 12 + 255) / 256, 256, 0, stream>>>(x, Xh, batch, gs, ge, out, cursor,
                                                      N, N * 12, out_size);
    // 2) hist (+ fused combine blocks)
    k_hist<<<dim3(EBLK + 36, 2), 256, 0, stream>>>(ei, ein, cntmat, E, N, NB, epb,
                                                   W0o, W0n, W0f, b0o, b0n, b0f,
                                                   W1o, W1n, W1f, b1o, b1n, b1f,
                                                   Wt, bc, gs, ge, rinv);
    k_bscan<<<dim3(NB, 2), 256, 0, stream>>>(cntmat, ebase, binfo, cursor, NB);
    k_part<<<dim3(EBLK, 2), 256, 0, stream>>>(ei, ew, ein, ewn, ebase, evb, E, NB, epb);
    k_nprep<<<dim3(NB, 2), 256, 0, stream>>>(evb, binfo, seg, dinv, E, N, NB);
    k_scat2<<<dim3(NB, 2), 256, 0, stream>>>(evb, binfo, seg, dinv, ev, E, N, NB);

    dim3 ag(((size_t)N * 64 + 255) / 256, 2);
    int mb = (N + 63) / 64;

    // layer 0
    k_agg<<<ag, 256, 0, stream>>>(Xh, seg, ev, ev + E, dinv, fAB, N);
    k_mmp<<<mb, 256, 0, stream>>>(fAB, Wt, bc, batch, gs, ge, rinv, out, Hh, 1, N);
    // layer 1
    k_agg<<<ag, 256, 0, stream>>>(Hh, seg, ev, ev + E, dinv, fAB, N);
    k_mmp<<<mb, 256, 0, stream>>>(fAB, Wt + (size_t)96 * 192, bc + DIM, batch, gs, ge, rinv,
                                  out + 64 * DIM, Hh, 0, N);
}

// Round 13
// 198.098 us; speedup vs baseline: 1.1132x; 1.1132x over previous
//
#include <hip/hip_runtime.h>
#include <hip/hip_bf16.h>
#include <hip/hip_fp16.h>

#define DIM 96
#define EBLK 256          // partition blocks per edge set
typedef unsigned int u32;
typedef unsigned long long u64;
typedef __attribute__((ext_vector_type(8))) _Float16 half8;
typedef __attribute__((ext_vector_type(4))) float f32x4;

__device__ __forceinline__ unsigned short f2h(float f) {
    union { unsigned short s; _Float16 h; } v; v.h = (_Float16)f; return v.s;
}
__device__ __forceinline__ u32 pkh(float lo, float hi) {
    return (u32)f2h(lo) | ((u32)f2h(hi) << 16);
}
__device__ __forceinline__ float hl(u32 u) {
    union { unsigned short s; _Float16 h; } v; v.s = (unsigned short)u; return (float)v.h;
}
__device__ __forceinline__ float hh(u32 u) {
    union { unsigned short s; _Float16 h; } v; v.s = (unsigned short)(u >> 16); return (float)v.h;
}

struct __align__(4) U3 { u32 a, b, c; };

// ---- setup: cast X -> fp16; bounds via unique-writer stores; zero out + cursor ----
__global__ __launch_bounds__(256) void k_cast0(
    const float* __restrict__ x, u32* __restrict__ Xh,
    const int* __restrict__ batch, int* __restrict__ gs, int* __restrict__ ge,
    float* __restrict__ outp, u32* __restrict__ cursor,
    int n, int total8, int osz)
{
    int i = blockIdx.x * 256 + threadIdx.x;
    if (i < total8) {
        const float4* xv = (const float4*)x;
        float4 a = xv[i * 2], b = xv[i * 2 + 1];
        uint4 o;
        o.x = pkh(a.x, a.y); o.y = pkh(a.z, a.w);
        o.z = pkh(b.x, b.y); o.w = pkh(b.z, b.w);
        ((uint4*)Xh)[i] = o;
    }
    if (i < n) {
        int b = batch[i];
        if (i == 0 || batch[i - 1] != b) gs[b] = i;        // unique writer
        if (i == n - 1 || batch[i + 1] != b) ge[b] = i + 1; // unique writer
    }
    if (i < osz) outp[i] = 0.f;
    if (i == 0) { cursor[0] = 0; cursor[1] = 0; }
}

// ---- pass A: per-block LDS histogram over buckets (dst>>7); extra blocks = combine ----
__global__ __launch_bounds__(256) void k_hist(
    const int* __restrict__ ei, const int* __restrict__ ein,
    u32* __restrict__ cntmat, int E, int n, int NB, int epb,
    const float* __restrict__ W0o, const float* __restrict__ W0n, const float* __restrict__ W0f,
    const float* __restrict__ b0o, const float* __restrict__ b0n, const float* __restrict__ b0f,
    const float* __restrict__ W1o, const float* __restrict__ W1n, const float* __restrict__ W1f,
    const float* __restrict__ b1o, const float* __restrict__ b1n, const float* __restrict__ b1f,
    unsigned short* __restrict__ Wt, float* __restrict__ bc,
    const int* __restrict__ gs, const int* __restrict__ ge, float* __restrict__ rinv)
{
    int set = blockIdx.y, tid = threadIdx.x;
    if (blockIdx.x >= EBLK) {
        // ---- fused k_combine (layer = blockIdx.y) ----
        if (blockIdx.y == 0 && blockIdx.x == EBLK && tid < 64) {
            int c = ge[tid] - gs[tid];
            if (c < 1) c = 1;
            rinv[tid] = 1.0f / (float)c;
        }
        int l = blockIdx.y;
        const float* Wo = l ? W1o : W0o;
        const float* Wn = l ? W1n : W0n;
        const float* Wf = l ? W1f : W0f;
        const float* bo = l ? b1o : b0o;
        const float* bn = l ? b1n : b0n;
        const float* bf = l ? b1f : b0f;
        unsigned short* wt = Wt + (size_t)l * 96 * 192;
        float* bcl = bc + l * DIM;
        int g = (blockIdx.x - EBLK) * 256 + tid;
        if (g >= DIM * DIM) return;
        int i = g / DIM, j = g % DIM;
        float so = 0.f, sn = 0.f;
        for (int k = 0; k < DIM; ++k) {
            so += Wo[i * DIM + k] * Wf[k * DIM + j];
            sn += Wn[i * DIM + k] * Wf[(DIM + k) * DIM + j];
        }
        wt[j * 192 + i]      = f2h(so);
        wt[j * 192 + 96 + i] = f2h(sn);
        if (i == 0) {
            float s = bf[j];
            for (int k = 0; k < DIM; ++k)
                s += bo[k] * Wf[k * DIM + j] + bn[k] * Wf[(DIM + k) * DIM + j];
            bcl[j] = s;
        }
        return;
    }
    __shared__ u32 hist[512];
    for (int t = tid; t < NB; t += 256) hist[t] = 0;
    __syncthreads();
    const int* D = (set ? ein : ei) + E;
    int lo = blockIdx.x * epb, hi = min(E, lo + epb);
    for (int e = lo + tid; e < hi; e += 256)
        atomicAdd(&hist[((u32)D[e]) >> 7], 1u);
    __syncthreads();
    u32* cm = cntmat + (size_t)set * NB * EBLK;
    for (int t = tid; t < NB; t += 256)
        cm[(size_t)t * EBLK + blockIdx.x] = hist[t];
}

// ---- pass B: per-bucket scan of 256 block counts; bucket base via cursor ----
__global__ __launch_bounds__(256) void k_bscan(
    const u32* __restrict__ cntmat, u32* __restrict__ ebase,
    u64* __restrict__ binfo, u32* __restrict__ cursor, int NB)
{
    int set = blockIdx.y, b = blockIdx.x, tid = threadIdx.x;
    int lane = tid & 63, wv = tid >> 6;
    const u32* cm = cntmat + ((size_t)set * NB + b) * EBLK;
    u32 v = cm[tid];
    u32 incl = v;
    #pragma unroll
    for (int d = 1; d < 64; d <<= 1) {
        u32 t = __shfl_up(incl, d);
        if (lane >= d) incl += t;
    }
    __shared__ u32 wt[4], woff[4], base_s;
    if (lane == 63) wt[wv] = incl;
    __syncthreads();
    if (tid == 0) {
        u32 run = 0;
        #pragma unroll
        for (int k = 0; k < 4; ++k) { woff[k] = run; run += wt[k]; }
        base_s = atomicAdd(&cursor[set], run);
        binfo[(size_t)set * NB + b] = ((u64)run << 32) | (u64)base_s;
    }
    __syncthreads();
    ebase[((size_t)set * NB + b) * EBLK + tid] = base_s + woff[wv] + incl - v;
}

// ---- pass C: partition edges into buckets: evb = [w32 | dl:7 | src:17] ----
__global__ __launch_bounds__(256) void k_part(
    const int* __restrict__ ei, const float* __restrict__ ew,
    const int* __restrict__ ein, const float* __restrict__ ewn,
    const u32* __restrict__ ebase, u64* __restrict__ evb,
    int E, int NB, int epb)
{
    int set = blockIdx.y, tid = threadIdx.x;
    const int*   I = set ? ein : ei;
    const float* W = set ? ewn : ew;
    __shared__ u32 hb[512];
    const u32* eb = ebase + (size_t)set * NB * EBLK;
    for (int t = tid; t < NB; t += 256) hb[t] = eb[(size_t)t * EBLK + blockIdx.x];
    __syncthreads();
    u64* out = evb + (size_t)set * E;
    int lo = blockIdx.x * epb, hi = min(E, lo + epb);
    for (int e = lo + tid; e < hi; e += 256) {
        int s = I[e], d = I[E + e];
        u32 wbits = __float_as_uint(W[e]);
        u32 pos = atomicAdd(&hb[(u32)d >> 7], 1u);
        out[pos] = ((u64)wbits << 32) | ((u32)(d & 127) << 17) | (u32)s;
    }
}

// ---- pass D: per-bucket node counts + weight sums (LDS) -> seg, dinv ----
__global__ __launch_bounds__(256) void k_nprep(
    const u64* __restrict__ evb, const u64* __restrict__ binfo,
    u64* __restrict__ seg, float* __restrict__ dinv, int E, int n, int NB)
{
    int set = blockIdx.y, b = blockIdx.x, tid = threadIdx.x;
    __shared__ u64 acc[128];
    if (tid < 128) acc[tid] = 0;
    __syncthreads();
    u64 bi = binfo[(size_t)set * NB + b];
    u32 base = (u32)bi, tot = (u32)(bi >> 32);
    const u64* ev = evb + (size_t)set * E;
    for (u32 j = tid; j < tot; j += 256) {
        u64 p = ev[base + j];
        u32 dl = ((u32)p >> 17) & 127;
        float w = __uint_as_float((u32)(p >> 32));
        u32 wfix = (u32)(w * 16777216.0f + 0.5f);
        atomicAdd(&acc[dl], ((u64)1 << 32) | (u64)wfix);
    }
    __syncthreads();
    __shared__ u32 wtot;
    u32 cnt = 0, excl = 0;
    if (tid < 128) {
        u64 a = acc[tid];
        cnt = (u32)(a >> 32);
        u32 incl = cnt;
        #pragma unroll
        for (int d = 1; d < 64; d <<= 1) {
            u32 t = __shfl_up(incl, d);
            if ((tid & 63) >= d) incl += t;
        }
        if (tid == 63) wtot = incl;
        excl = incl - cnt;
    }
    __syncthreads();
    if (tid >= 64 && tid < 128) excl += wtot;
    int gnode = b * 128 + tid;
    if (tid < 128 && gnode < n) {
        u32 st = base + excl;
        seg[(size_t)set * n + gnode] = ((u64)(st + cnt) << 32) | (u64)st;
        u64 a = acc[tid];
        dinv[(size_t)set * n + gnode] =
            rsqrtf((float)(u32)a * 5.9604644775390625e-8f + 1.0f);
    }
}

// ---- pass E: bucket -> node-exact CSR with norm folded: ev = [norm_f32 | src] ----
__global__ __launch_bounds__(256) void k_scat2(
    const u64* __restrict__ evb, const u64* __restrict__ binfo,
    const u64* __restrict__ seg, const float* __restrict__ dinv,
    u64* __restrict__ evout, int E, int n, int NB)
{
    int set = blockIdx.y, b = blockIdx.x, tid = threadIdx.x;
    __shared__ u32 rk[128];
    __shared__ u32 st_l[128];
    __shared__ float dv_l[128];
    const float* dv = dinv + (size_t)set * n;
    if (tid < 128) {
        rk[tid] = 0;
        int gnode = b * 128 + tid;
        if (gnode < n) {
            st_l[tid] = (u32)seg[(size_t)set * n + gnode];
            dv_l[tid] = dv[gnode];
        }
    }
    __syncthreads();
    u64 bi = binfo[(size_t)set * NB + b];
    u32 base = (u32)bi, tot = (u32)(bi >> 32);
    const u64* evi = evb + (size_t)set * E;
    u64* out = evout + (size_t)set * E;
    for (u32 j = tid; j < tot; j += 256) {
        u64 p = evi[base + j];
        u32 src = (u32)p & 0x1ffffu;
        u32 dl = ((u32)p >> 17) & 127;
        float w = __uint_as_float((u32)(p >> 32));
        float nrm = dv_l[dl] * w * dv[src];
        u32 slot = st_l[dl] + atomicAdd(&rk[dl], 1u);
        out[slot] = ((u64)__float_as_uint(nrm) << 32) | (u64)src;
    }
}

// ------- aggregation: 16-lane group OWNS one node (wave = 4 nodes); dense 8-batches -------
__global__ __launch_bounds__(256) void k_agg(
    const u32* __restrict__ Xh,
    const u64* __restrict__ seg,
    const u64* __restrict__ ev_o, const u64* __restrict__ ev_n,
    const float* __restrict__ dinv,
    u32* __restrict__ fAB, int n)
{
    int gw = (blockIdx.x * 256 + threadIdx.x) >> 6;    // wave index
    int lane = threadIdx.x & 63;
    int g = lane >> 4, sl = lane & 15;
    int node = gw * 4 + g;
    if (node >= n) return;
    const u64* ev; const u64* sg; const float* dv; int co;
    if (blockIdx.y) { sg = seg + n; ev = ev_n; dv = dinv + n; co = 48; }
    else            { sg = seg;     ev = ev_o; dv = dinv;     co = 0; }

    float dr = dv[node];
    float d2 = dr * dr;
    U3 xs = *(const U3*)(Xh + (size_t)node * 48 + sl * 3);
    float a0 = d2 * hl(xs.a), a1 = d2 * hh(xs.a);
    float a2 = d2 * hl(xs.b), a3 = d2 * hh(xs.b);
    float a4 = d2 * hl(xs.c), a5 = d2 * hh(xs.c);

    u64 sv = sg[node];
    int s = (int)(u32)sv, e = (int)(u32)(sv >> 32);
    for (int j = s; j < e; j += 8) {
        // 8 dense predicated slots; invalid -> weight 0, row = own node (L1-hot)
        float ww[8]; int uu[8];
        #pragma unroll
        for (int k = 0; k < 8; ++k) {
            int jj = j + k;
            bool v = jj < e;
            u64 t = ev[v ? jj : j];
            ww[k] = v ? __uint_as_float((u32)(t >> 32)) : 0.f;
            uu[k] = v ? (int)(u32)t : node;
        }
        U3 xx[8];
        #pragma unroll
        for (int k = 0; k < 8; ++k)
            xx[k] = *(const U3*)(Xh + (size_t)uu[k] * 48 + sl * 3);
        #pragma unroll
        for (int k = 0; k < 8; ++k) {
            float w = ww[k];
            a0 += w * hl(xx[k].a); a1 += w * hh(xx[k].a);
            a2 += w * hl(xx[k].b); a3 += w * hh(xx[k].b);
            a4 += w * hl(xx[k].c); a5 += w * hh(xx[k].c);
        }
    }
    U3 o;
    o.a = pkh(a0, a1); o.b = pkh(a2, a3); o.c = pkh(a4, a5);
    *(U3*)(fAB + (size_t)node * 96 + co + sl * 3) = o;
}

// ---------------- MFMA GEMM: relu(fAB[N][192]fp16 @ Wt + bias); pool; fp16 H ----------------
__global__ __launch_bounds__(256) void k_mmp(
    const u32* __restrict__ fAB, const unsigned short* __restrict__ Wtg,
    const float* __restrict__ bias, const int* __restrict__ batch,
    const int* __restrict__ gs, const int* __restrict__ ge,
    const float* __restrict__ rinv, float* __restrict__ outp,
    u32* __restrict__ Hh, int writeH, int n)
{
    __shared__ unsigned short sW[96 * 200];
    __shared__ float tile[64][100];
    int tid = threadIdx.x;
    for (int m = tid; m < 2304; m += 256) {
        int j = m / 24, k = (m % 24) * 8;
        *(uint4*)&sW[j * 200 + k] = *(const uint4*)&Wtg[j * 192 + k];
    }
    __syncthreads();
    int r0 = blockIdx.x * 64;
    int rows = min(64, n - r0);
    int lane = tid & 63, wv = tid >> 6;
    int rl = lane & 15;
    int kg = lane >> 4;
    int rowg = r0 + wv * 16 + rl;
    int rc = min(rowg, n - 1);
    const half8* Arow = (const half8*)(fAB + (size_t)rc * 96);
    f32x4 acc[6];
    #pragma unroll
    for (int c = 0; c < 6; ++c) acc[c] = (f32x4){0.f, 0.f, 0.f, 0.f};
    #pragma unroll
    for (int t = 0; t < 6; ++t) {
        half8 a = Arow[t * 4 + kg];
        #pragma unroll
        for (int c = 0; c < 6; ++c) {
            half8 b = *(const half8*)&sW[(c * 16 + rl) * 200 + t * 32 + kg * 8];
            acc[c] = __builtin_amdgcn_mfma_f32_16x16x32_f16(a, b, acc[c], 0, 0, 0);
        }
    }
    #pragma unroll
    for (int c = 0; c < 6; ++c) {
        int col = c * 16 + rl;
        float bs = bias[col];
        #pragma unroll
        for (int q = 0; q < 4; ++q) {
            int lr = wv * 16 + kg * 4 + q;
            tile[lr][col] = fmaxf(acc[c][q] + bs, 0.f);
        }
    }
    __syncthreads();
    if (writeH) {
        for (int m = tid; m < rows * 48; m += 256) {
            int row = m / 48, cp = m % 48;
            Hh[(size_t)(r0 + row) * 48 + cp] = pkh(tile[row][cp * 2], tile[row][cp * 2 + 1]);
        }
    }
    if (tid < DIM) {
        int gfirst = batch[r0], glast = batch[r0 + rows - 1];
        for (int g = gfirst; g <= glast; ++g) {
            int lo = max(gs[g] - r0, 0), hi = min(ge[g] - r0, rows);
            if (lo < hi) {
                float s = 0.f;
                for (int r = lo; r < hi; ++r) s += tile[r][tid];
                atomicAdd(&outp[g * DIM + tid], s * rinv[g]);
            }
        }
    }
}

extern "C" void kernel_launch(void* const* d_in, const int* in_sizes, int n_in,
                              void* d_out, int out_size, void* d_ws, size_t ws_size,
                              hipStream_t stream)
{
    const float* x     = (const float*)d_in[0];
    const int*   ei    = (const int*)d_in[1];
    const float* ew    = (const float*)d_in[2];
    const int*   batch = (const int*)d_in[3];
    const int*   ein   = (const int*)d_in[4];
    const float* ewn   = (const float*)d_in[5];
    const float* W0o = (const float*)d_in[7];
    const float* b0o = (const float*)d_in[8];
    const float* W0n = (const float*)d_in[9];
    const float* b0n = (const float*)d_in[10];
    const float* W0f = (const float*)d_in[11];
    const float* b0f = (const float*)d_in[12];
    const float* W1o = (const float*)d_in[13];
    const float* b1o = (const float*)d_in[14];
    const float* W1n = (const float*)d_in[15];
    const float* b1n = (const float*)d_in[16];
    const float* W1f = (const float*)d_in[17];
    const float* b1f = (const float*)d_in[18];

    const int N = in_sizes[0] / DIM;
    const int E = in_sizes[2];
    float* out = (float*)d_out;
    const int NB = (N + 127) >> 7;
    const int epb = (E + EBLK - 1) / EBLK;

    char* ws = (char*)d_ws;
    size_t off = 0;
    auto alloc = [&](size_t bytes) -> char* {
        char* p = ws + off;
        off += (bytes + 255) & ~(size_t)255;
        return p;
    };
    u32*   cntmat = (u32*)alloc((size_t)2 * NB * EBLK * 4);
    u32*   ebase  = (u32*)alloc((size_t)2 * NB * EBLK * 4);
    u64*   binfo  = (u64*)alloc((size_t)2 * NB * 8);
    u64*   evb    = (u64*)alloc((size_t)2 * E * 8);
    u64*   ev     = (u64*)alloc((size_t)2 * E * 8);
    u64*   seg    = (u64*)alloc((size_t)2 * N * 8);
    float* dinv   = (float*)alloc((size_t)2 * N * 4);
    u32*   Xh     = (u32*)alloc((size_t)N * 48 * 4);
    u32*   Hh     = (u32*)alloc((size_t)N * 48 * 4);
    u32*   fAB    = (u32*)alloc((size_t)N * 96 * 4);
    unsigned short* Wt = (unsigned short*)alloc((size_t)2 * 96 * 192 * 2);
    float* bc     = (float*)alloc(2 * DIM * 4);
    float* rinv   = (float*)alloc(64 * 4);
    int*   gs     = (int*)alloc(64 * 4);
    int*   ge     = (int*)alloc(64 * 4);
    u32*   cursor = (u32*)alloc(2 * 4);

    // 1) setup: cast + bounds + zero out/cursor
    k_cast0<<<(N * 12 + 255) / 256, 256, 0, stream>>>(x, Xh, batch, gs, ge, out, cursor,
                                                      N, N * 12, out_size);
    // 2) hist (+ fused combine blocks)
    k_hist<<<dim3(EBLK + 36, 2), 256, 0, stream>>>(ei, ein, cntmat, E, N, NB, epb,
                                                   W0o, W0n, W0f, b0o, b0n, b0f,
                                                   W1o, W1n, W1f, b1o, b1n, b1f,
                                                   Wt, bc, gs, ge, rinv);
    k_bscan<<<dim3(NB, 2), 256, 0, stream>>>(cntmat, ebase, binfo, cursor, NB);
    k_part<<<dim3(EBLK, 2), 256, 0, stream>>>(ei, ew, ein, ewn, ebase, evb, E, NB, epb);
    k_nprep<<<dim3(NB, 2), 256, 0, stream>>>(evb, binfo, seg, dinv, E, N, NB);
    k_scat2<<<dim3(NB, 2), 256, 0, stream>>>(evb, binfo, seg, dinv, ev, E, N, NB);

    // agg: wave = 4 nodes -> block of 256 covers 16 nodes
    dim3 ag((N + 15) / 16, 2);
    int mb = (N + 63) / 64;

    // layer 0
    k_agg<<<ag, 256, 0, stream>>>(Xh, seg, ev, ev + E, dinv, fAB, N);
    k_mmp<<<mb, 256, 0, stream>>>(fAB, Wt, bc, batch, gs, ge, rinv, out, Hh, 1, N);
    // layer 1
    k_agg<<<ag, 256, 0, stream>>>(Hh, seg, ev, ev + E, dinv, fAB, N);
    k_mmp<<<mb, 256, 0, stream>>>(fAB, Wt + (size_t)96 * 192, bc + DIM, batch, gs, ge, rinv,
                                  out + 64 * DIM, Hh, 0, N);
}